// Round 1
// baseline (120.247 us; speedup 1.0000x reference)
//
#include <hip/hip_runtime.h>
#include <stdint.h>

#define IN_F   4096
#define OUT_F  768
#define NB     8
#define BATCH  4096
#define WCOLS  (OUT_F*NB)   // 6144

typedef short  bf16x8  __attribute__((ext_vector_type(8)));
typedef float  f32x4   __attribute__((ext_vector_type(4)));
typedef unsigned short ushort8 __attribute__((ext_vector_type(8)));

__device__ __forceinline__ unsigned short f2bf(float f){
    union { float f; uint32_t u; } v; v.f = f;
    uint32_t u = v.u;
    u += 0x7FFFu + ((u >> 16) & 1u);   // round-to-nearest-even
    return (unsigned short)(u >> 16);
}

__device__ __forceinline__ void gload16(const void* g, void* l){
    __builtin_amdgcn_global_load_lds(
        (const __attribute__((address_space(1))) unsigned int*)g,
        (__attribute__((address_space(3))) unsigned int*)l, 16, 0, 0);
}

// ---------------- kernel 1: latent f32 -> bf16 ; zero accumulators ----------
__global__ void prep_latent(const float* __restrict__ lat,
                            unsigned short* __restrict__ abf,
                            float* __restrict__ acc){
    if (blockIdx.x == 0 && threadIdx.x < 4) acc[threadIdx.x] = 0.f;
    int idx = (blockIdx.x * 256 + threadIdx.x) * 8;   // 8 floats / thread
    const float4* p = (const float4*)(lat + idx);
    float4 a = p[0], b = p[1];
    ushort8 o;
    o[0]=f2bf(a.x); o[1]=f2bf(a.y); o[2]=f2bf(a.z); o[3]=f2bf(a.w);
    o[4]=f2bf(b.x); o[5]=f2bf(b.y); o[6]=f2bf(b.z); o[7]=f2bf(b.w);
    *(ushort8*)(abf + idx) = o;
}

// ---------------- kernel 2: sigmoid-decode weight -> int_weights^T (bf16) ---
// grid (IN_F/64, OUT_F/64), 256 threads. Tile: 64 k-rows x 64 n-cols.
__global__ void decode_weight(const float* __restrict__ w,
                              unsigned short* __restrict__ bt,
                              float* __restrict__ acc){
    __shared__ unsigned short tile[64][70];   // [n][k], 140B row stride
    __shared__ float part[4];
    const int tid = threadIdx.x;
    const int k0 = blockIdx.x * 64;
    const int n0 = blockIdx.y * 64;
    const int j     = tid & 63;        // n within tile
    const int ibase = (tid >> 6) * 16; // k within tile
    float pol = 0.f;
    #pragma unroll 4
    for (int r = 0; r < 16; ++r){
        int i = ibase + r;
        const float4* src = (const float4*)(w + (size_t)(k0+i)*WCOLS + (size_t)(n0+j)*8);
        float4 a = src[0], b = src[1];
        float x[8] = {a.x,a.y,a.z,a.w,b.x,b.y,b.z,b.w};
        float p[8];
        #pragma unroll
        for (int q = 0; q < 8; ++q){
            p[q] = 1.f / (1.f + __expf(-x[q]));
            pol += p[q] * (1.f - p[q]);
        }
        float iw = p[0] + 2.f*p[1] + 4.f*p[2] + 8.f*p[3]
                 + 16.f*p[4] + 32.f*p[5] + 64.f*p[6] - 128.f*p[7];
        tile[j][i] = f2bf(iw);
    }
    // polarize reduce: wave then block
    #pragma unroll
    for (int off = 32; off; off >>= 1) pol += __shfl_down(pol, off);
    if ((tid & 63) == 0) part[tid >> 6] = pol;
    __syncthreads();
    // write transposed tile coalesced: 8B per thread per row
    const int nrow = tid >> 4;
    const int kb   = (tid & 15) * 4;
    #pragma unroll
    for (int q = 0; q < 4; ++q){
        int n = nrow + q*16;
        uint2 v;
        v.x = *(const unsigned int*)&tile[n][kb];
        v.y = *(const unsigned int*)&tile[n][kb+2];
        *(uint2*)(bt + (size_t)(n0+n)*IN_F + k0 + kb) = v;
    }
    if (tid == 0) atomicAdd(&acc[1], part[0]+part[1]+part[2]+part[3]);
}

// ---------------- kernel 3: bf16 GEMM (m97 structure) + fused loss ----------
#define BM 128
#define BN 128
#define BK 64

__launch_bounds__(512)
__global__ void gemm_loss(const unsigned short* __restrict__ abf,
                          const unsigned short* __restrict__ bt,
                          const float* __restrict__ ts,
                          float* __restrict__ acc){
    __shared__ unsigned short As[BM*BK];   // 16KB, linear [row][64k]
    __shared__ unsigned short Bs[BN*BK];   // 16KB, linear [col][64k]
    __shared__ float part[8];
    const int tid = threadIdx.x;
    const int w   = tid >> 6;
    const int l   = tid & 63;
    const int s   = l & 15, g = l >> 4;
    const int sw  = s & 7;
    const int wr  = w >> 2, wc = w & 3;    // 2 (rows) x 4 (cols) waves
    const int m0  = blockIdx.x * BM;
    const int n0  = blockIdx.y * BN;

    f32x4 accv[4][2];
    #pragma unroll
    for (int m = 0; m < 4; ++m)
        #pragma unroll
        for (int n = 0; n < 2; ++n)
            accv[m][n] = (f32x4){0.f,0.f,0.f,0.f};

    // staging: thread t covers LDS row t>>3, 16B chunk t&7 (source XOR-swizzled)
    const int srow = tid >> 3;
    const int sc   = tid & 7;
    const int swz  = ((sc ^ (srow & 7)) << 3);  // element offset of fetched chunk
    const unsigned short* aSrc0 = abf + (size_t)(m0 + srow)     * IN_F + swz;
    const unsigned short* aSrc1 = abf + (size_t)(m0 + 64 + srow)* IN_F + swz;
    const unsigned short* bSrc0 = bt  + (size_t)(n0 + srow)     * IN_F + swz;
    const unsigned short* bSrc1 = bt  + (size_t)(n0 + 64 + srow)* IN_F + swz;
    char* AsB = (char*)As;
    char* BsB = (char*)Bs;
    const int wbase = w * 1024;            // per-wave 64 lanes x 16B

    const int arow = wr*64 + s;            // LDS row for A frags (+m*16)
    const int bcol = wc*32 + s;            // LDS row for B frags (+n*16)

    for (int kt = 0; kt < IN_F/BK; ++kt){
        const int ko = kt * BK;
        gload16(aSrc0 + ko, AsB + wbase);
        gload16(aSrc1 + ko, AsB + 8192 + wbase);
        gload16(bSrc0 + ko, BsB + wbase);
        gload16(bSrc1 + ko, BsB + 8192 + wbase);
        __syncthreads();                   // drains vmcnt before barrier
        #pragma unroll
        for (int kk = 0; kk < 2; ++kk){
            bf16x8 af[4], bfr[2];
            const int chunk = ((kk*4 + g) ^ sw) << 4;   // swizzled 16B chunk
            #pragma unroll
            for (int m = 0; m < 4; ++m)
                af[m] = *(const bf16x8*)(AsB + (arow + m*16)*128 + chunk);
            #pragma unroll
            for (int n = 0; n < 2; ++n)
                bfr[n] = *(const bf16x8*)(BsB + (bcol + n*16)*128 + chunk);
            #pragma unroll
            for (int m = 0; m < 4; ++m)
                #pragma unroll
                for (int n = 0; n < 2; ++n)
                    accv[m][n] = __builtin_amdgcn_mfma_f32_16x16x32_bf16(
                        af[m], bfr[n], accv[m][n], 0, 0, 0);
        }
        __syncthreads();
    }

    // fused epilogue: decode true_sum bits, accumulate (pred - int_sum)^2
    float local = 0.f;
    #pragma unroll
    for (int m = 0; m < 4; ++m){
        int rbase = m0 + wr*64 + m*16 + g*4;
        #pragma unroll
        for (int n = 0; n < 2; ++n){
            int col = n0 + wc*32 + n*16 + s;
            const float* tsp = ts + (size_t)rbase*WCOLS + (size_t)col*8;
            #pragma unroll
            for (int jj = 0; jj < 4; ++jj){
                const float4* q = (const float4*)(tsp + (size_t)jj*WCOLS);
                float4 x = q[0], y = q[1];
                float isum = x.x + 2.f*x.y + 4.f*x.z + 8.f*x.w
                           + 16.f*y.x + 32.f*y.y + 64.f*y.z - 128.f*y.w;
                float d = accv[m][n][jj] - isum;
                local += d*d;
            }
        }
    }
    #pragma unroll
    for (int off = 32; off; off >>= 1) local += __shfl_down(local, off);
    if (l == 0) part[w] = local;
    __syncthreads();
    if (tid == 0){
        float ssum = 0.f;
        #pragma unroll
        for (int i = 0; i < 8; ++i) ssum += part[i];
        atomicAdd(&acc[0], ssum);
    }
}

// ---------------- kernel 4: finalize ----------------------------------------
__global__ void finalize(const float* __restrict__ acc, float* __restrict__ out){
    out[0] = acc[0] * (1.0f / ((float)BATCH * (float)OUT_F * 128.0f));
    out[1] = acc[1] * (1.0f / ((float)IN_F * (float)WCOLS));
}

extern "C" void kernel_launch(void* const* d_in, const int* in_sizes, int n_in,
                              void* d_out, int out_size, void* d_ws, size_t ws_size,
                              hipStream_t stream){
    const float* latent   = (const float*)d_in[0];
    const float* true_sum = (const float*)d_in[1];
    const float* weight   = (const float*)d_in[2];
    float* acc = (float*)d_ws;
    unsigned short* abf = (unsigned short*)((char*)d_ws + 1024);
    unsigned short* bt  = (unsigned short*)((char*)d_ws + 1024 + (size_t)BATCH*IN_F*2);
    float* out = (float*)d_out;

    prep_latent<<<(BATCH*IN_F)/(256*8), 256, 0, stream>>>(latent, abf, acc);
    decode_weight<<<dim3(IN_F/64, OUT_F/64), 256, 0, stream>>>(weight, bt, acc);
    gemm_loss<<<dim3(BATCH/BM, OUT_F/BN), 512, 0, stream>>>(abf, bt, true_sum, acc);
    finalize<<<1, 1, 0, stream>>>(acc, out);
}